// Round 9
// baseline (452.145 us; speedup 1.0000x reference)
//
#include <hip/hip_runtime.h>

// Problem constants (from reference setup_inputs)
#define DIN 200      // K (floats per x row)
#define DH  100      // J
#define NKT 7        // k tiles of 32 (224, padded)
#define MARGIN 2e-3f // |delta| below this -> exact fp64 fixup (~8 sigma of f16 err)
#define LROW 204     // padded LDS row stride in floats (204%32=12 -> 2-way banks, free)
#define TR   32      // rows per tile
#define BUFF (26 * 256)   // floats per tile buffer (26 x 1KB chunks >= 32*204)
#define NT   32      // tiles per block
#define RPB  (NT * TR)    // 1024 rows per block
#define NPASS 2      // INSTRUMENTATION: 2 identical passes so the hot dispatch
                     // (~500us) outranks the ~250us harness fill dispatches in
                     // rocprof top-k. Pass 2 rewrites identical values ->
                     // deterministic, idempotent. Remove after diagnosis.

typedef _Float16 half8 __attribute__((ext_vector_type(8)));
typedef float f32x4 __attribute__((ext_vector_type(4)));

__device__ inline half8 cvt8(float4 u, float4 v) {
  half8 h;
  h[0] = (_Float16)u.x; h[1] = (_Float16)u.y;
  h[2] = (_Float16)u.z; h[3] = (_Float16)u.w;
  h[4] = (_Float16)v.x; h[5] = (_Float16)v.y;
  h[6] = (_Float16)v.z; h[7] = (_Float16)v.w;
  return h;
}

// ---------------- hot kernel: f16-MFMA GEMM sign, w-in-regs / x-in-LDS ----------------
template <bool HAVE_WS>
__global__ __launch_bounds__(256)
void entmax_sign_mfma(const float* __restrict__ x,
                      const float* __restrict__ w_out,
                      const float* __restrict__ b_out,
                      const float* __restrict__ w_cat,
                      const float* __restrict__ b_cat,
                      const float* __restrict__ w2,
                      const float* __restrict__ b2,
                      float* __restrict__ out,
                      float* __restrict__ dws) {
  __shared__ float xs[2 * BUFF];          // double-buffered 32-row x tile, 53248 B
  __shared__ float parts[2][4][TR];       // per-wave j-partials, double-buffered, 1 KB

  const int tid  = threadIdx.x;
  const int lane = tid & 63;
  const int wid  = tid >> 6;
  const int arow = lane & 15;   // A-row / B-col within 16-tile
  const int qid  = lane >> 4;   // quad: k sub-offset qid*8

  const float db = b_cat[0] - b_cat[1];
  const float c0 = w2[0] + b2[0];
  const float c1 = w2[1] + b2[0];

  // ---- w fragments in REGISTERS: wave owns j-tiles 2*wid, 2*wid+1 ----
  half8 wf0[NKT], wf1[NKT];
  float bjv0, djv0, bjv1, djv1;
  {
    const int j0 = (2 * wid) * 16 + arow;
    const int j1 = (2 * wid + 1) * 16 + arow;   // wave 3: jt7 -> dummy zeros
    bjv0 = (j0 < DH) ? b_out[j0] : 0.f;
    djv0 = (j0 < DH) ? (w_cat[j0] - w_cat[DH + j0]) : 0.f;
    bjv1 = (j1 < DH) ? b_out[j1] : 0.f;
    djv1 = (j1 < DH) ? (w_cat[j1] - w_cat[DH + j1]) : 0.f;
#pragma unroll
    for (int kt = 0; kt < NKT; ++kt) {
      const int k = kt * 32 + qid * 8;
      half8 h0 = {}, h1 = {};
      if (k < DIN) {
        if (j0 < DH) {
          float4 a = *(const float4*)(w_out + j0 * DIN + k);
          float4 b = *(const float4*)(w_out + j0 * DIN + k + 4);
          h0 = cvt8(a, b);
        }
        if (j1 < DH) {
          float4 a = *(const float4*)(w_out + j1 * DIN + k);
          float4 b = *(const float4*)(w_out + j1 * DIN + k + 4);
          h1 = cvt8(a, b);
        }
      }
      wf0[kt] = h0; wf1[kt] = h1;
    }
  }

  const int blockBase = blockIdx.x * RPB;

  // All 4 waves co-stage tile t: 26 real 1KB chunks + 2 dummies -> 7 loads/wave
  // (uniform so vmcnt literals are exact). LDS dst linear (wave-uniform base +
  // lane*16); LROW padding realized by per-lane GLOBAL source mapping.
  auto stage = [&](int buf, int t) {
    const int r0 = blockBase + t * TR;
#pragma unroll
    for (int i = 0; i < 7; ++i) {
      int c = 4 * i + wid;
      if (c >= 26) c = wid;               // dummy: re-issue own first chunk
      const int fo = c * 256 + lane * 4;  // float offset in buffer
      int row = fo / LROW;  row = (row < TR) ? row : TR - 1;
      int col = fo - row * LROW;  col = (col < DIN) ? col : 0;  // 4-aligned, in-row
      const float* src = x + (size_t)(r0 + row) * DIN + col;
      float* dst = xs + buf * BUFF + c * 256;
      __builtin_amdgcn_global_load_lds(
          (const __attribute__((address_space(1))) void*)src,
          (__attribute__((address_space(3))) void*)dst, 16, 0, 0);
    }
  };

#pragma unroll 1
  for (int pass = 0; pass < NPASS; ++pass) {
    stage(0, 0);
    stage(1, 1);

#pragma unroll 1
    for (int t = 0; t < NT; ++t) {
      // Drain exactly loads(t). Over-draining older residual stores is safe.
      if (t == 0)           { asm volatile("s_waitcnt vmcnt(7)" ::: "memory"); }
      else if (t == NT - 1) { asm volatile("s_waitcnt vmcnt(2)" ::: "memory"); }
      else                  { asm volatile("s_waitcnt vmcnt(9)" ::: "memory"); }
      __builtin_amdgcn_sched_barrier(0);
      __builtin_amdgcn_s_barrier();        // all waves' loads(t) landed

      const float* xb = xs + (t & 1) * BUFF;

      f32x4 acc[2][2];                     // [rg][jtl], compile-time indices
#pragma unroll
      for (int rg = 0; rg < 2; ++rg)
#pragma unroll
        for (int jl = 0; jl < 2; ++jl) acc[rg][jl] = (f32x4){0.f, 0.f, 0.f, 0.f};

#pragma unroll
      for (int kt = 0; kt < NKT; ++kt) {
#pragma unroll
        for (int rg = 0; rg < 2; ++rg) {
          half8 a = {};
          if (kt < 6 || qid == 0) {        // kt6 valid only for quad 0
            const float* p = xb + (rg * 16 + arow) * LROW + kt * 32 + qid * 8;
            float4 u = *(const float4*)p;
            float4 v = *(const float4*)(p + 4);
            a = cvt8(u, v);
          }
          acc[rg][0] = __builtin_amdgcn_mfma_f32_16x16x32_f16(a, wf0[kt], acc[rg][0], 0, 0, 0);
          acc[rg][1] = __builtin_amdgcn_mfma_f32_16x16x32_f16(a, wf1[kt], acc[rg][1], 0, 0, 0);
        }
      }

      // ---- epilogue: relu + dw-weight, 16-lane j-reduce, publish partials ----
      f32x4 part[2];
#pragma unroll
      for (int rg = 0; rg < 2; ++rg)
#pragma unroll
        for (int r = 0; r < 4; ++r)
          part[rg][r] = fmaxf(acc[rg][0][r] + bjv0, 0.f) * djv0 +
                        fmaxf(acc[rg][1][r] + bjv1, 0.f) * djv1;
#pragma unroll
      for (int m = 1; m < 16; m <<= 1)
#pragma unroll
        for (int rg = 0; rg < 2; ++rg)
#pragma unroll
          for (int r = 0; r < 4; ++r)
            part[rg][r] += __shfl_xor(part[rg][r], m, 64);

      if (arow == 0) {
        *(f32x4*)(&parts[t & 1][wid][0 * 16 + qid * 4]) = part[0];
        *(f32x4*)(&parts[t & 1][wid][1 * 16 + qid * 4]) = part[1];
      }

      asm volatile("s_waitcnt lgkmcnt(0)" ::: "memory");  // my ds reads+writes done
      __builtin_amdgcn_sched_barrier(0);
      __builtin_amdgcn_s_barrier();        // buf t free to overwrite; parts visible

      // ---- decision: wave w owns local rows [8w, 8w+8) ----
      if (lane < 8) {
        const int rl = wid * 8 + lane;
        const float delta = parts[t & 1][0][rl] + parts[t & 1][1][rl] +
                            parts[t & 1][2][rl] + parts[t & 1][3][rl] + db;
        const int row = blockBase + t * TR + rl;
        out[row] = (delta >= 0.f) ? c0 : c1;
        if (HAVE_WS) {
          dws[row] = delta;
        } else if (fabsf(delta) < MARGIN) {
          // Tiny-ws fallback: lane-local exact fp64 (cold, improbable path)
          const float* xr = x + (size_t)row * DIN;
          double s = (double)b_cat[0] - (double)b_cat[1];
          for (int j = 0; j < DH; ++j) {
            double a = (double)b_out[j];
            for (int k = 0; k < DIN; ++k)
              a += (double)xr[k] * (double)w_out[j * DIN + k];
            if (a > 0.0) s += a * ((double)w_cat[j] - (double)w_cat[DH + j]);
          }
          out[row] = (s >= 0.0) ? c0 : c1;
        }
      }

      if (t + 2 < NT) stage(t & 1, t + 2);
    }
  }
}

// ---------------- cold kernel: exact-sign fixup of near-boundary rows ----------------
__global__ __launch_bounds__(256, 4)
void entmax_fixup(const float* __restrict__ x,
                  const float* __restrict__ w_out,
                  const float* __restrict__ b_out,
                  const float* __restrict__ w_cat,
                  const float* __restrict__ b_cat,
                  const float* __restrict__ w2,
                  const float* __restrict__ b2,
                  float* __restrict__ out,
                  const float* __restrict__ dws) {
  const int tid  = threadIdx.x;
  const int lane = tid & 63;
  const long long wave = (long long)blockIdx.x * 4 + (tid >> 6);
  const int base = (int)(wave * 64);

  const float d = dws[base + lane];
  unsigned long long m = __ballot(fabsf(d) < MARGIN);
  if (!m) return;

  const float c0 = w2[0] + b2[0];
  const float c1 = w2[1] + b2[0];
  const int j0 = lane, j1 = lane + 64;

  while (m) {
    const int b = __ffsll(m) - 1;
    m &= m - 1;
    const int row = base + b;
    const float* xr = x + (size_t)row * DIN;
    double a0 = 0.0, a1 = 0.0;
#pragma unroll 4
    for (int k = 0; k < DIN; ++k) {
      double xd = (double)xr[k];
      a0 += xd * (double)w_out[j0 * DIN + k];
      if (j1 < DH) a1 += xd * (double)w_out[j1 * DIN + k];
    }
    double t = 0.0;
    {
      double u = a0 + (double)b_out[j0];
      if (u > 0.0) t += u * ((double)w_cat[j0] - (double)w_cat[DH + j0]);
    }
    if (j1 < DH) {
      double u = a1 + (double)b_out[j1];
      if (u > 0.0) t += u * ((double)w_cat[j1] - (double)w_cat[DH + j1]);
    }
#pragma unroll
    for (int s = 1; s < 64; s <<= 1) t += __shfl_xor(t, s, 64);
    t += (double)b_cat[0] - (double)b_cat[1];
    if (lane == 0) out[row] = (t >= 0.0) ? c0 : c1;
  }
}

extern "C" void kernel_launch(void* const* d_in, const int* in_sizes, int n_in,
                              void* d_out, int out_size, void* d_ws, size_t ws_size,
                              hipStream_t stream) {
  const float* x     = (const float*)d_in[0];
  const float* w_out = (const float*)d_in[1];
  const float* b_out = (const float*)d_in[2];
  const float* w_cat = (const float*)d_in[3];
  const float* b_cat = (const float*)d_in[4];
  const float* w2    = (const float*)d_in[5];
  const float* b2    = (const float*)d_in[6];
  float* out = (float*)d_out;

  const int N = in_sizes[0] / DIN;     // 524288
  const int nblk = N / RPB;            // 512 blocks x 1024 rows = exactly 2/CU

  if (ws_size >= (size_t)N * sizeof(float)) {
    float* dws = (float*)d_ws;
    entmax_sign_mfma<true><<<nblk, 256, 0, stream>>>(x, w_out, b_out, w_cat,
                                                     b_cat, w2, b2, out, dws);
    entmax_fixup<<<N / 256, 256, 0, stream>>>(x, w_out, b_out, w_cat, b_cat,
                                              w2, b2, out, dws);
  } else {
    entmax_sign_mfma<false><<<nblk, 256, 0, stream>>>(x, w_out, b_out, w_cat,
                                                      b_cat, w2, b2, out, nullptr);
  }
}

// Round 10
// 268.307 us; speedup vs baseline: 1.6852x; 1.6852x over previous
//
#include <hip/hip_runtime.h>

// Problem constants (from reference setup_inputs)
#define DIN 200      // K (floats per x row); 50 float4s
#define DH  100      // J
#define NKT 7        // k tiles of 32 (224, padded)
#define MARGIN 2e-3f // |delta| below this -> exact fp64 fixup
#define TR   32      // rows per tile
#define NT   16      // tiles per block -> 512 rows/block
#define RPB  (NT * TR)

typedef _Float16 half8 __attribute__((ext_vector_type(8)));
typedef _Float16 half4 __attribute__((ext_vector_type(4)));
typedef float f32x4 __attribute__((ext_vector_type(4)));

__device__ inline half8 cvt8(float4 u, float4 v) {
  half8 h;
  h[0] = (_Float16)u.x; h[1] = (_Float16)u.y;
  h[2] = (_Float16)u.z; h[3] = (_Float16)u.w;
  h[4] = (_Float16)v.x; h[5] = (_Float16)v.y;
  h[6] = (_Float16)v.z; h[7] = (_Float16)v.w;
  return h;
}
__device__ inline half4 cvt4(float4 u) {
  half4 h;
  h[0] = (_Float16)u.x; h[1] = (_Float16)u.y;
  h[2] = (_Float16)u.z; h[3] = (_Float16)u.w;
  return h;
}

// ---------------- hot kernel: f16-MFMA GEMM sign ----------------
// x staged f32->f16 ONCE into fragment-ordered LDS (conflict-free b128 reads),
// w frags in registers (j-split across waves), single x buffer + 2 barriers.
template <bool HAVE_WS>
__global__ __launch_bounds__(256, 4)
void entmax_sign_mfma(const float* __restrict__ x,
                      const float* __restrict__ w_out,
                      const float* __restrict__ b_out,
                      const float* __restrict__ w_cat,
                      const float* __restrict__ b_cat,
                      const float* __restrict__ w2,
                      const float* __restrict__ b2,
                      float* __restrict__ out,
                      float* __restrict__ dws) {
  // A-frags: frag f = rg*7+kt (rg=row/16, kt=k/32); lane l holds
  // x[rg*16+(l&15)][kt*32+(l>>4)*8 .. +8] as 8 f16 (16B). 14 frags x 1 KB.
  __shared__ _Float16 axf[14 * 512];      // 14336 B
  __shared__ float parts[2][4][TR];       // 1 KB, dbuf by t&1

  const int tid  = threadIdx.x;
  const int lane = tid & 63;
  const int wid  = tid >> 6;
  const int arow = lane & 15;
  const int qid  = lane >> 4;

  const float db = b_cat[0] - b_cat[1];
  const float c0 = w2[0] + b2[0];
  const float c1 = w2[1] + b2[0];

  // Zero the pad slots of frags (rg,6): k in [200,224) never staged; leftover
  // LDS bits could be f16 NaN -> NaN*0 in MFMA. One-time, persists (never
  // overwritten: staging only writes k<200 slots).
  for (int t2 = tid; t2 < 768; t2 += 256) {
    const int fi = t2 / 384, r2 = t2 - fi * 384;
    axf[(fi * 7 + 6) * 512 + 128 + r2] = (_Float16)0.f;
  }

  // ---- w fragments in registers: wave owns j-tiles 2*wid, 2*wid+1 ----
  half8 wf0[NKT], wf1[NKT];
  float bjv0, djv0, bjv1, djv1;
  {
    const int j0 = (2 * wid) * 16 + arow;
    const int j1 = (2 * wid + 1) * 16 + arow;   // wave 3: jt7 -> zeros
    bjv0 = (j0 < DH) ? b_out[j0] : 0.f;
    djv0 = (j0 < DH) ? (w_cat[j0] - w_cat[DH + j0]) : 0.f;
    bjv1 = (j1 < DH) ? b_out[j1] : 0.f;
    djv1 = (j1 < DH) ? (w_cat[j1] - w_cat[DH + j1]) : 0.f;
#pragma unroll
    for (int kt = 0; kt < NKT; ++kt) {
      const int k = kt * 32 + qid * 8;
      half8 h0 = {}, h1 = {};
      if (k < DIN) {
        if (j0 < DH) {
          float4 a = *(const float4*)(w_out + j0 * DIN + k);
          float4 b = *(const float4*)(w_out + j0 * DIN + k + 4);
          h0 = cvt8(a, b);
        }
        if (j1 < DH) {
          float4 a = *(const float4*)(w_out + j1 * DIN + k);
          float4 b = *(const float4*)(w_out + j1 * DIN + k + 4);
          h1 = cvt8(a, b);
        }
      }
      wf0[kt] = h0; wf1[kt] = h1;
    }
  }

  const int blockBase = blockIdx.x * RPB;
  const float4* xf4 = (const float4*)x;

  // Staging identity: thread = (row_l = tid&31, c = tid>>5); i-th load is
  // col4 = c + 8i (i=0..5; i=6 only c<2 -> wave-uniform per wave).
  // Writes land at frag (rg=row_l>>4, kt=i), lane slot (row_l&15)+(c>>1)*16,
  // half (c&1): base precomputed, +512*i per step. ~2-way write banks (free).
  const int row_l = tid & 31;
  const int cseg  = tid >> 5;
  const int wbase = (row_l >> 4) * 7 * 512 + ((row_l & 15) + (cseg >> 1) * 16) * 8
                  + (cseg & 1) * 4;

  float4 u0, u1, u2, u3, u4, u5, u6;
#define LOADT(T)                                                            \
  {                                                                         \
    const float4* xt = xf4 + (size_t)(blockBase + (T) * TR + row_l) * 50 + cseg; \
    u0 = xt[0];  u1 = xt[8];  u2 = xt[16];                                  \
    u3 = xt[24]; u4 = xt[32]; u5 = xt[40];                                  \
    if (cseg < 2) u6 = xt[48];                                              \
  }

  LOADT(0);

#pragma unroll 1
  for (int t = 0; t < NT; ++t) {
    asm volatile("s_waitcnt vmcnt(0)" ::: "memory");   // loads(t) arrived
    __builtin_amdgcn_sched_barrier(0);

    // ---- cvt + fragment-ordered LDS write ----
    *(half4*)(&axf[wbase + 0 * 512]) = cvt4(u0);
    *(half4*)(&axf[wbase + 1 * 512]) = cvt4(u1);
    *(half4*)(&axf[wbase + 2 * 512]) = cvt4(u2);
    *(half4*)(&axf[wbase + 3 * 512]) = cvt4(u3);
    *(half4*)(&axf[wbase + 4 * 512]) = cvt4(u4);
    *(half4*)(&axf[wbase + 5 * 512]) = cvt4(u5);
    if (cseg < 2) *(half4*)(&axf[wbase + 6 * 512]) = cvt4(u6);

    if (t + 1 < NT) LOADT(t + 1);                      // prefetch next tile

    asm volatile("s_waitcnt lgkmcnt(0)" ::: "memory"); // my writes done
    __builtin_amdgcn_sched_barrier(0);
    __builtin_amdgcn_s_barrier();                      // B1: tile staged

    // ---- compute: conflict-free frag reads + 28 MFMAs ----
    f32x4 acc[2][2];
#pragma unroll
    for (int rg = 0; rg < 2; ++rg)
#pragma unroll
      for (int jl = 0; jl < 2; ++jl) acc[rg][jl] = (f32x4){0.f, 0.f, 0.f, 0.f};

#pragma unroll
    for (int kt = 0; kt < NKT; ++kt)
#pragma unroll
      for (int rg = 0; rg < 2; ++rg) {
        half8 a = *(half8*)(&axf[(rg * 7 + kt) * 512 + lane * 8]);
        acc[rg][0] = __builtin_amdgcn_mfma_f32_16x16x32_f16(a, wf0[kt], acc[rg][0], 0, 0, 0);
        acc[rg][1] = __builtin_amdgcn_mfma_f32_16x16x32_f16(a, wf1[kt], acc[rg][1], 0, 0, 0);
      }

    // ---- epilogue: relu + dw-weight, 16-lane j-reduce, publish partials ----
    f32x4 part[2];
#pragma unroll
    for (int rg = 0; rg < 2; ++rg)
#pragma unroll
      for (int r = 0; r < 4; ++r)
        part[rg][r] = fmaxf(acc[rg][0][r] + bjv0, 0.f) * djv0 +
                      fmaxf(acc[rg][1][r] + bjv1, 0.f) * djv1;
#pragma unroll
    for (int m = 1; m < 16; m <<= 1)
#pragma unroll
      for (int rg = 0; rg < 2; ++rg)
#pragma unroll
        for (int r = 0; r < 4; ++r)
          part[rg][r] += __shfl_xor(part[rg][r], m, 64);

    if (arow == 0) {
      *(f32x4*)(&parts[t & 1][wid][0 * 16 + qid * 4]) = part[0];
      *(f32x4*)(&parts[t & 1][wid][1 * 16 + qid * 4]) = part[1];
    }

    asm volatile("s_waitcnt lgkmcnt(0)" ::: "memory"); // frag reads + parts done
    __builtin_amdgcn_sched_barrier(0);
    __builtin_amdgcn_s_barrier();                      // B2: buf free, parts visible

    // ---- decision: wave w owns local rows [8w, 8w+8) ----
    if (lane < 8) {
      const int rl = wid * 8 + lane;
      const float delta = parts[t & 1][0][rl] + parts[t & 1][1][rl] +
                          parts[t & 1][2][rl] + parts[t & 1][3][rl] + db;
      const int row = blockBase + t * TR + rl;
      out[row] = (delta >= 0.f) ? c0 : c1;
      if (HAVE_WS) {
        dws[row] = delta;
      } else if (fabsf(delta) < MARGIN) {
        // Tiny-ws fallback: lane-local exact fp64 (cold, improbable path)
        const float* xr = x + (size_t)row * DIN;
        double s = (double)b_cat[0] - (double)b_cat[1];
        for (int j = 0; j < DH; ++j) {
          double a = (double)b_out[j];
          for (int k = 0; k < DIN; ++k)
            a += (double)xr[k] * (double)w_out[j * DIN + k];
          if (a > 0.0) s += a * ((double)w_cat[j] - (double)w_cat[DH + j]);
        }
        out[row] = (s >= 0.0) ? c0 : c1;
      }
    }
  }
#undef LOADT
}

// ---------------- cold kernel: exact-sign fixup, lane=k coalesced ----------------
__global__ __launch_bounds__(256, 4)
void entmax_fixup(const float* __restrict__ x,
                  const float* __restrict__ w_out,
                  const float* __restrict__ b_out,
                  const float* __restrict__ w_cat,
                  const float* __restrict__ b_cat,
                  const float* __restrict__ w2,
                  const float* __restrict__ b2,
                  float* __restrict__ out,
                  const float* __restrict__ dws) {
  const int tid  = threadIdx.x;
  const int lane = tid & 63;
  const long long wave = (long long)blockIdx.x * 4 + (tid >> 6);
  const int base = (int)(wave * 64);

  const float d = dws[base + lane];
  unsigned long long m = __ballot(fabsf(d) < MARGIN);
  if (!m) return;

  const float c0 = w2[0] + b2[0];
  const float c1 = w2[1] + b2[0];
  const double dbd = (double)b_cat[0] - (double)b_cat[1];
  const int k3 = lane + ((lane < 8) ? 192 : 0);   // valid addr for all lanes

  while (m) {
    const int b = __ffsll(m) - 1;
    m &= m - 1;
    const int row = base + b;
    const float* xr = x + (size_t)row * DIN;
    // x row in registers (lane=k split: k = lane, lane+64, lane+128, [lane+192])
    const double x0 = (double)xr[lane];
    const double x1 = (double)xr[lane + 64];
    const double x2 = (double)xr[lane + 128];
    const double x3 = (lane < 8) ? (double)xr[lane + 192] : 0.0;
    double s = 0.0;
#pragma unroll 2
    for (int j = 0; j < DH; ++j) {
      const float* wr = w_out + j * DIN;     // coalesced: lanes consecutive
      double p = x0 * (double)wr[lane] + x1 * (double)wr[lane + 64] +
                 x2 * (double)wr[lane + 128] + x3 * (double)wr[k3];
#pragma unroll
      for (int sh = 1; sh < 64; sh <<= 1) p += __shfl_xor(p, sh, 64);
      const double u = p + (double)b_out[j];
      if (u > 0.0) s += u * ((double)w_cat[j] - (double)w_cat[DH + j]);
    }
    s += dbd;
    if (lane == 0) out[row] = (s >= 0.0) ? c0 : c1;
  }
}

extern "C" void kernel_launch(void* const* d_in, const int* in_sizes, int n_in,
                              void* d_out, int out_size, void* d_ws, size_t ws_size,
                              hipStream_t stream) {
  const float* x     = (const float*)d_in[0];
  const float* w_out = (const float*)d_in[1];
  const float* b_out = (const float*)d_in[2];
  const float* w_cat = (const float*)d_in[3];
  const float* b_cat = (const float*)d_in[4];
  const float* w2    = (const float*)d_in[5];
  const float* b2    = (const float*)d_in[6];
  float* out = (float*)d_out;

  const int N = in_sizes[0] / DIN;     // 524288
  const int nblk = N / RPB;            // 1024 blocks x 512 rows

  if (ws_size >= (size_t)N * sizeof(float)) {
    float* dws = (float*)d_ws;
    entmax_sign_mfma<true><<<nblk, 256, 0, stream>>>(x, w_out, b_out, w_cat,
                                                     b_cat, w2, b2, out, dws);
    entmax_fixup<<<N / 256, 256, 0, stream>>>(x, w_out, b_out, w_cat, b_cat,
                                              w2, b2, out, dws);
  } else {
    entmax_sign_mfma<false><<<nblk, 256, 0, stream>>>(x, w_out, b_out, w_cat,
                                                      b_cat, w2, b2, out, nullptr);
  }
}